// Round 2
// baseline (3565.555 us; speedup 1.0000x reference)
//
#include <hip/hip_runtime.h>
#include <math.h>

#define NSTEPS 50
#define NHID   64
#define NFEAT  11

// tanh(x) = 1 - 2/(e^{2x}+1); v_exp + v_rcp, ~3e-7 abs err (absorbed by fp32
// state quantization -> no trajectory divergence; verified absmax unchanged).
__device__ __forceinline__ float fast_tanh(float x) {
    float e = __expf(x + x);                       // inf -> rcp->0 -> +1; 0 -> -1
    return 1.0f - 2.0f * __builtin_amdgcn_rcpf(e + 1.0f);
}

// lane-pair exchange: quad_perm(1,0,3,2) == xor-1 lane swap. Pure VALU (1 inst),
// bit-preserving, partner lane always active (pairs never split by the guard).
__device__ __forceinline__ float dpp_xor1(float x) {
    int r = __builtin_amdgcn_update_dpp(0, __float_as_int(x), 0xB1, 0xF, 0xF, true);
    return __int_as_float(r);
}

__global__ __launch_bounds__(256, 4)
void phys_mlp_kernel(const float* __restrict__ inputs,
                     const float* __restrict__ W1,
                     const float* __restrict__ b1,
                     const float* __restrict__ W2,
                     const float* __restrict__ b2,
                     const float* __restrict__ W3,
                     const float* __restrict__ b3,
                     const float* __restrict__ grav,
                     const float* __restrict__ fric,
                     float* __restrict__ out,
                     int nb) {
    // 2 lanes per trajectory: lane parity picks rows [0,32) or [32,64) of every
    // hidden layer. Grid doubles -> 4 waves/SIMD (was the hard 2-wave cap).
    // All row-split weights live in LDS (natural layout, NO transpose needed:
    // L1/L2 are k-outer so we stream row k of W1/W2 directly).
    __shared__ __attribute__((aligned(16))) float sW2[NHID * NHID];
    __shared__ __attribute__((aligned(16))) float sW1[NFEAT * NHID];
    __shared__ __attribute__((aligned(16))) float sB1[NHID];
    __shared__ __attribute__((aligned(16))) float sB2[NHID];

    {   // stage once per block; coalesced float4 copies
        int tid = threadIdx.x;
        for (int i = tid; i < NHID * NHID / 4; i += 256)
            ((float4*)sW2)[i] = ((const float4*)W2)[i];
        for (int i = tid; i < NFEAT * NHID / 4; i += 256)
            ((float4*)sW1)[i] = ((const float4*)W1)[i];
        if (tid < NHID / 4) ((float4*)sB1)[tid] = ((const float4*)b1)[tid];
        else if (tid >= 64 && tid < 64 + NHID / 4)
            ((float4*)sB2)[tid - 64] = ((const float4*)b2)[tid - 64];
    }
    __syncthreads();

    int gtid = blockIdx.x * 256 + threadIdx.x;
    int b = gtid >> 1;                             // trajectory index
    if (b >= nb) return;
    const int  half = threadIdx.x & 1;             // 0: rows 0-31, 1: rows 32-63
    const bool odd  = (half != 0);

    const float* myW1 = sW1 + (half << 5);         // my 32 columns of each row
    const float* myW2 = sW2 + (half << 5);
    const float* myB1 = sB1 + (half << 5);
    const float* myB2 = sB2 + (half << 5);

    const float DTF = 1.0f / 30.0f;
    float pg = __fmul_rn(grav[0], 40.0f);
    float fr = fabsf(fric[0]);

    // state = inputs[b, 0, :] (both lanes load the same 32 B -> identical state)
    const float4* in4 = (const float4*)(inputs + (size_t)b * NSTEPS * 8);
    float4 s0 = in4[0], s1 = in4[1];
    float p1x = s0.x, p1y = s0.y, p2x = s0.z, p2y = s0.w;
    float v1x = s1.x, v1y = s1.y, v2x = s1.z, v2y = s1.w;

    // even lane stores the pos quad, odd lane the vel quad (same 32 B coverage)
    float* op = out + (size_t)b * NSTEPS * 8 + (half << 2);

    #pragma unroll 1
    for (int t = 0; t < NSTEPS; ++t) {
        *(float4*)op = odd ? make_float4(v1x, v1y, v2x, v2y)
                           : make_float4(p1x, p1y, p2x, p2y);
        op += 8;
        if (t == NSTEPS - 1) break;                // 50th update discarded by scan

        // ---------------- features (np op order; duplicated on both lanes) ------
        float feats[NFEAT];
        {
            float r = __fsqrt_rn(__fadd_rn(__fmul_rn(p1x, p1x), __fmul_rn(p1y, p1y)));
            feats[0] = r;
            feats[1] = atan2f(p1y, p1x);
            feats[2] = __fdiv_rn(__fadd_rn(__fmul_rn(p1x, v1x), __fmul_rn(p1y, v1y)),
                                 __fadd_rn(r, 1e-6f));
            float vt = __fdiv_rn(__fsub_rn(__fmul_rn(p1x, v1y), __fmul_rn(p1y, v1x)),
                                 __fadd_rn(__fmul_rn(r, r), 1e-6f));
            feats[3] = vt;
            feats[4] = __fmul_rn(r, vt);
        }
        {
            float r = __fsqrt_rn(__fadd_rn(__fmul_rn(p2x, p2x), __fmul_rn(p2y, p2y)));
            feats[5] = r;
            feats[6] = atan2f(p2y, p2x);
            feats[7] = __fdiv_rn(__fadd_rn(__fmul_rn(p2x, v2x), __fmul_rn(p2y, v2y)),
                                 __fadd_rn(r, 1e-6f));
            float vt = __fdiv_rn(__fsub_rn(__fmul_rn(p2x, v2y), __fmul_rn(p2y, v2x)),
                                 __fadd_rn(__fmul_rn(r, r), 1e-6f));
            feats[8] = vt;
            feats[9] = __fmul_rn(r, vt);
        }
        {
            float dx = __fsub_rn(p2x, p1x), dy = __fsub_rn(p2y, p1y);
            feats[10] = __fsqrt_rn(__fadd_rn(__fmul_rn(dx, dx), __fmul_rn(dy, dy)));
        }

        // ---------------- layer 1: rows half*32+[0,32), k-outer ------------------
        // per-row chain: b1[r] then k ascending -> bit-identical to the 1-thread
        // kernel's h1[r]. Weights: row k of W1, my 32 cols, ds_read_b128 with
        // immediate offsets (2 distinct addrs/wave = free 2-way broadcast).
        float acc[32];
        #pragma unroll
        for (int q = 0; q < 8; ++q) {
            float4 bq = *(const float4*)(myB1 + 4 * q);
            acc[4 * q + 0] = bq.x; acc[4 * q + 1] = bq.y;
            acc[4 * q + 2] = bq.z; acc[4 * q + 3] = bq.w;
        }
        #pragma unroll
        for (int k = 0; k < NFEAT; ++k) {
            float f = feats[k];
            #pragma unroll
            for (int q = 0; q < 8; ++q) {
                float4 w = *(const float4*)(myW1 + k * NHID + 4 * q);
                acc[4 * q + 0] = fmaf(f, w.x, acc[4 * q + 0]);
                acc[4 * q + 1] = fmaf(f, w.y, acc[4 * q + 1]);
                acc[4 * q + 2] = fmaf(f, w.z, acc[4 * q + 2]);
                acc[4 * q + 3] = fmaf(f, w.w, acc[4 * q + 3]);
            }
        }
        float h[32];
        #pragma unroll
        for (int j = 0; j < 32; ++j) h[j] = fast_tanh(acc[j]);

        // ---------------- layer 2: rows half*32+[0,32), k-outer ------------------
        // h1[k] for k<32 lives on even lanes, k>=32 on odd; one DPP swap + select
        // per k broadcasts the canonical value to both lanes. 32 independent
        // accumulator chains; per-row FMA order = canonical k-ascending.
        float a2[32];
        #pragma unroll
        for (int q = 0; q < 8; ++q) {
            float4 bq = *(const float4*)(myB2 + 4 * q);
            a2[4 * q + 0] = bq.x; a2[4 * q + 1] = bq.y;
            a2[4 * q + 2] = bq.z; a2[4 * q + 3] = bq.w;
        }
        #pragma unroll
        for (int k = 0; k < NHID; ++k) {
            float own = h[k & 31];
            float oth = dpp_xor1(own);
            float hk  = (k < 32) ? (odd ? oth : own) : (odd ? own : oth);
            #pragma unroll
            for (int q = 0; q < 8; ++q) {
                float4 w = *(const float4*)(myW2 + k * NHID + 4 * q);
                a2[4 * q + 0] = fmaf(hk, w.x, a2[4 * q + 0]);
                a2[4 * q + 1] = fmaf(hk, w.y, a2[4 * q + 1]);
                a2[4 * q + 2] = fmaf(hk, w.z, a2[4 * q + 2]);
                a2[4 * q + 3] = fmaf(hk, w.w, a2[4 * q + 3]);
            }
        }
        float tt[32];
        #pragma unroll
        for (int j = 0; j < 32; ++j) tt[j] = fast_tanh(a2[j]);

        // ---------------- layer 3: duplicated, canonical ascending-j chain -------
        float c0 = b3[0], c1 = b3[1];
        #pragma unroll
        for (int j = 0; j < NHID; ++j) {
            float own = tt[j & 31];
            float oth = dpp_xor1(own);
            float tj  = (j < 32) ? (odd ? oth : own) : (odd ? own : oth);
            c0 = fmaf(tj, W3[2 * j],     c0);
            c1 = fmaf(tj, W3[2 * j + 1], c1);
        }
        float corr0 = __fmul_rn(c0, 0.1f);
        float corr1 = __fmul_rn(c1, 0.1f);

        // ---------------- integrate (non-fused, np op order; both lanes) --------
        float ax1 = __fadd_rn(__fsub_rn(0.0f, __fmul_rn(fr, v1x)), corr0);
        float ay1 = __fadd_rn(__fsub_rn(pg,   __fmul_rn(fr, v1y)), corr1);
        float ax2 = __fadd_rn(__fsub_rn(0.0f, __fmul_rn(fr, v2x)), corr0);
        float ay2 = __fadd_rn(__fsub_rn(pg,   __fmul_rn(fr, v2y)), corr1);
        float nv1x = __fadd_rn(v1x, __fmul_rn(ax1, DTF));
        float nv1y = __fadd_rn(v1y, __fmul_rn(ay1, DTF));
        float nv2x = __fadd_rn(v2x, __fmul_rn(ax2, DTF));
        float nv2y = __fadd_rn(v2y, __fmul_rn(ay2, DTF));
        float np1x = __fadd_rn(p1x, __fmul_rn(nv1x, DTF));
        float np1y = __fadd_rn(p1y, __fmul_rn(nv1y, DTF));
        float np2x = __fadd_rn(p2x, __fmul_rn(nv2x, DTF));
        float np2y = __fadd_rn(p2y, __fmul_rn(nv2y, DTF));

        // ---------------- bounce (mask on pre-clip pos) --------------------------
        nv1x = (np1x < 20.0f || np1x > 780.0f) ? __fmul_rn(-0.8f, nv1x) : nv1x;
        np1x = fminf(fmaxf(np1x, 20.0f), 780.0f);
        nv1y = (np1y < 20.0f || np1y > 580.0f) ? __fmul_rn(-0.8f, nv1y) : nv1y;
        np1y = fminf(fmaxf(np1y, 20.0f), 580.0f);
        nv2x = (np2x < 20.0f || np2x > 780.0f) ? __fmul_rn(-0.8f, nv2x) : nv2x;
        np2x = fminf(fmaxf(np2x, 20.0f), 780.0f);
        nv2y = (np2y < 20.0f || np2y > 580.0f) ? __fmul_rn(-0.8f, nv2y) : nv2y;
        np2y = fminf(fmaxf(np2y, 20.0f), 580.0f);

        p1x = np1x; p1y = np1y; p2x = np2x; p2y = np2y;
        v1x = nv1x; v1y = nv1y; v2x = nv2x; v2y = nv2y;
    }
}

extern "C" void kernel_launch(void* const* d_in, const int* in_sizes, int n_in,
                              void* d_out, int out_size, void* d_ws, size_t ws_size,
                              hipStream_t stream) {
    const float* inputs = (const float*)d_in[0];
    const float* W1     = (const float*)d_in[1];
    const float* b1     = (const float*)d_in[2];
    const float* W2     = (const float*)d_in[3];
    const float* b2     = (const float*)d_in[4];
    const float* W3     = (const float*)d_in[5];
    const float* b3     = (const float*)d_in[6];
    const float* grav   = (const float*)d_in[7];
    const float* fric   = (const float*)d_in[8];
    float* out = (float*)d_out;
    (void)d_ws; (void)ws_size;

    int nb = in_sizes[0] / (NSTEPS * 8);
    int nthreads = nb * 2;                         // 2 lanes per trajectory
    int blocks = (nthreads + 255) / 256;
    phys_mlp_kernel<<<blocks, 256, 0, stream>>>(inputs, W1, b1, W2, b2, W3, b3,
                                                grav, fric, out, nb);
}